// Round 1
// baseline (110.899 us; speedup 1.0000x reference)
//
#include <hip/hip_runtime.h>

#define HID 128
#define EPSM 1e-3f

// ---------------------------------------------------------------------------
// Pack all per-neuron weights into one 32-float record so the main loop reads
// 8x float4 (ds_read_b128 broadcast) per neuron.
// Layout per neuron i (float index):
//  0: Wm1[i,0]  1: Wm1[i,1]  2: bm1[i]    3: Wm2[0,i]
//  4: Wm2[1,i]  5: Wm2[2,i]  6: Wm2[3,i]  7: Wg1[i,0]
//  8: Wg1[i,1]  9: bg1[i]   10: Wg2[0,i] 11: Wg2[1,i]
// 12: Wc1[i,0] 13: Wc1[i,1] 14: Wc1[i,2] 15: Wc1[i,3]
// 16: bc1[i]   17: Wc2[0,i] 18: Wc2[1,i] 19: Wc2[2,i]
// 20: Wc2[3,i] 21: Wt1[i,0] 22: Wt1[i,1] 23: Wt1[i,2]
// 24: Wt1[i,3] 25: Wt1[i,4] 26: Wt1[i,5] 27: bt1[i]
// 28: Wt2[0,i] 29: Wt2[1,i] 30: pad      31: pad
// Tail at float offset 4096: bm2[0..3], bc2[0..3], bg2[0..1], bt2[0..1]
// ---------------------------------------------------------------------------
__global__ void phynn_pack(const float* __restrict__ Wm1, const float* __restrict__ bm1,
                           const float* __restrict__ Wm2, const float* __restrict__ bm2,
                           const float* __restrict__ Wc1, const float* __restrict__ bc1,
                           const float* __restrict__ Wc2, const float* __restrict__ bc2,
                           const float* __restrict__ Wg1, const float* __restrict__ bg1,
                           const float* __restrict__ Wg2, const float* __restrict__ bg2,
                           const float* __restrict__ Wt1, const float* __restrict__ bt1,
                           const float* __restrict__ Wt2, const float* __restrict__ bt2,
                           float* __restrict__ P)
{
    int i = threadIdx.x;
    if (i < HID) {
        float* p = P + i * 32;
        p[0]  = Wm1[2*i];     p[1]  = Wm1[2*i+1];  p[2]  = bm1[i];      p[3]  = Wm2[i];
        p[4]  = Wm2[128+i];   p[5]  = Wm2[256+i];  p[6]  = Wm2[384+i];  p[7]  = Wg1[2*i];
        p[8]  = Wg1[2*i+1];   p[9]  = bg1[i];      p[10] = Wg2[i];      p[11] = Wg2[128+i];
        p[12] = Wc1[4*i];     p[13] = Wc1[4*i+1];  p[14] = Wc1[4*i+2];  p[15] = Wc1[4*i+3];
        p[16] = bc1[i];       p[17] = Wc2[i];      p[18] = Wc2[128+i];  p[19] = Wc2[256+i];
        p[20] = Wc2[384+i];   p[21] = Wt1[6*i];    p[22] = Wt1[6*i+1];  p[23] = Wt1[6*i+2];
        p[24] = Wt1[6*i+3];   p[25] = Wt1[6*i+4];  p[26] = Wt1[6*i+5];  p[27] = bt1[i];
        p[28] = Wt2[i];       p[29] = Wt2[128+i];  p[30] = 0.f;         p[31] = 0.f;
    }
    if (i == HID) {
        float* t = P + 4096;
        t[0] = bm2[0]; t[1] = bm2[1]; t[2]  = bm2[2]; t[3]  = bm2[3];
        t[4] = bc2[0]; t[5] = bc2[1]; t[6]  = bc2[2]; t[7]  = bc2[3];
        t[8] = bg2[0]; t[9] = bg2[1]; t[10] = bt2[0]; t[11] = bt2[1];
    }
}

__device__ __forceinline__ float fast_tanh(float x)
{
    // tanh(x) = 1 - 2/(exp(2x)+1); no overflow for large |x| (inf -> 1, 0 -> -1)
    float e = __expf(2.0f * x);
    float r = __builtin_amdgcn_rcpf(e + 1.0f);
    return __builtin_fmaf(-2.0f, r, 1.0f);
}

#define NPE 2  // batch elements per thread

__global__ __launch_bounds__(256, 4) void phynn_main(
    const float2* __restrict__ q, const float2* __restrict__ qd, const float2* __restrict__ u,
    const float* __restrict__ P, float* __restrict__ out, int B)
{
    __shared__ float4 W[1024 + 3];

    const float4* Pv = (const float4*)P;
    #pragma unroll
    for (int k = 0; k < 4; ++k) W[threadIdx.x + 256 * k] = Pv[threadIdx.x + 256 * k];
    if (threadIdx.x < 3) W[1024 + threadIdx.x] = Pv[1024 + threadIdx.x];
    __syncthreads();

    const int half = B >> 1;
    const int tid  = blockIdx.x * 256 + threadIdx.x;
    if (tid >= half) return;

    int e[NPE];
    e[0] = tid;
    e[1] = tid + half;

    float q0[NPE], q1[NPE], d0[NPE], d1[NPE], u0[NPE], u1[NPE];
    #pragma unroll
    for (int s = 0; s < NPE; ++s) {
        float2 vq = q[e[s]];  q0[s] = vq.x; q1[s] = vq.y;
        float2 vd = qd[e[s]]; d0[s] = vd.x; d1[s] = vd.y;
        float2 vu = u[e[s]];  u0[s] = vu.x; u1[s] = vu.y;
    }

    float aL0[NPE] = {}, aL2[NPE] = {}, aL3[NPE] = {};
    float aC0[NPE] = {}, aC1[NPE] = {}, aC2[NPE] = {}, aC3[NPE] = {};
    float aG0[NPE] = {}, aG1[NPE] = {};
    float aT0[NPE] = {}, aT1[NPE] = {};

    #pragma unroll 2
    for (int i = 0; i < HID; ++i) {
        const float4 v0 = W[i*8+0];
        const float4 v1 = W[i*8+1];
        const float4 v2 = W[i*8+2];
        const float4 v3 = W[i*8+3];
        const float4 v4 = W[i*8+4];
        const float4 v5 = W[i*8+5];
        const float4 v6 = W[i*8+6];
        const float4 v7 = W[i*8+7];
        #pragma unroll
        for (int s = 0; s < NPE; ++s) {
            // mass MLP hidden neuron (skip tril-zeroed output index 1)
            float am = fmaf(v0.x, q0[s], fmaf(v0.y, q1[s], v0.z));
            float hm = fast_tanh(am);
            aL0[s] = fmaf(v0.w, hm, aL0[s]);
            aL2[s] = fmaf(v1.y, hm, aL2[s]);
            aL3[s] = fmaf(v1.z, hm, aL3[s]);
            // gravity MLP
            float ag = fmaf(v1.w, q0[s], fmaf(v2.x, q1[s], v2.y));
            float hg = fast_tanh(ag);
            aG0[s] = fmaf(v2.z, hg, aG0[s]);
            aG1[s] = fmaf(v2.w, hg, aG1[s]);
            // Coriolis MLP
            float ac = fmaf(v3.x, q0[s], fmaf(v3.y, q1[s],
                       fmaf(v3.z, d0[s], fmaf(v3.w, d1[s], v4.x))));
            float hc = fast_tanh(ac);
            aC0[s] = fmaf(v4.y, hc, aC0[s]);
            aC1[s] = fmaf(v4.z, hc, aC1[s]);
            aC2[s] = fmaf(v4.w, hc, aC2[s]);
            aC3[s] = fmaf(v5.x, hc, aC3[s]);
            // torque MLP
            float at = fmaf(v5.y, q0[s], fmaf(v5.z, q1[s],
                       fmaf(v5.w, d0[s], fmaf(v6.x, d1[s],
                       fmaf(v6.y, u0[s], fmaf(v6.z, u1[s], v6.w))))));
            float ht = fast_tanh(at);
            aT0[s] = fmaf(v7.x, ht, aT0[s]);
            aT1[s] = fmaf(v7.y, ht, aT1[s]);
        }
    }

    const float4 bm2v = W[1024];
    const float4 bc2v = W[1025];
    const float4 bgt  = W[1026];

    float*  outf = out;
    float2* o_qdd = (float2*)outf;
    float4* o_M   = (float4*)(outf + (size_t)2 * B);
    float4* o_C   = (float4*)(outf + (size_t)6 * B);
    float2* o_g   = (float2*)(outf + (size_t)10 * B);
    float2* o_t   = (float2*)(outf + (size_t)12 * B);

    #pragma unroll
    for (int s = 0; s < NPE; ++s) {
        float l00 = aL0[s] + bm2v.x;
        float l10 = aL2[s] + bm2v.z;
        float l11 = aL3[s] + bm2v.w;
        float M00 = fmaf(l00, l00, EPSM);
        float M01 = l00 * l10;
        float M11 = fmaf(l10, l10, fmaf(l11, l11, EPSM));

        float C00 = aC0[s] + bc2v.x;
        float C01 = aC1[s] + bc2v.y;
        float C10 = aC2[s] + bc2v.z;
        float C11 = aC3[s] + bc2v.w;

        float g0 = aG0[s] + bgt.x;
        float g1 = aG1[s] + bgt.y;
        float t0 = aT0[s] + bgt.z;
        float t1 = aT1[s] + bgt.w;

        float rhs0 = u0[s] - fmaf(C00, d0[s], C01 * d1[s]) - g0 - t0;
        float rhs1 = u1[s] - fmaf(C10, d0[s], C11 * d1[s]) - g1 - t1;

        float det  = fmaf(M00, M11, -(M01 * M01));
        float qdd0 = fmaf(M11, rhs0, -(M01 * rhs1)) / det;
        float qdd1 = fmaf(M00, rhs1, -(M01 * rhs0)) / det;

        o_qdd[e[s]] = make_float2(qdd0, qdd1);
        o_M[e[s]]   = make_float4(M00, M01, M01, M11);
        o_C[e[s]]   = make_float4(C00, C01, C10, C11);
        o_g[e[s]]   = make_float2(g0, g1);
        o_t[e[s]]   = make_float2(t0, t1);
    }
}

extern "C" void kernel_launch(void* const* d_in, const int* in_sizes, int n_in,
                              void* d_out, int out_size, void* d_ws, size_t ws_size,
                              hipStream_t stream)
{
    const float* q   = (const float*)d_in[0];
    const float* qd  = (const float*)d_in[1];
    const float* u   = (const float*)d_in[2];
    const float* Wm1 = (const float*)d_in[3];
    const float* bm1 = (const float*)d_in[4];
    const float* Wm2 = (const float*)d_in[5];
    const float* bm2 = (const float*)d_in[6];
    const float* Wc1 = (const float*)d_in[7];
    const float* bc1 = (const float*)d_in[8];
    const float* Wc2 = (const float*)d_in[9];
    const float* bc2 = (const float*)d_in[10];
    const float* Wg1 = (const float*)d_in[11];
    const float* bg1 = (const float*)d_in[12];
    const float* Wg2 = (const float*)d_in[13];
    const float* bg2 = (const float*)d_in[14];
    const float* Wt1 = (const float*)d_in[15];
    const float* bt1 = (const float*)d_in[16];
    const float* Wt2 = (const float*)d_in[17];
    const float* bt2 = (const float*)d_in[18];

    const int B = in_sizes[0] / 2;
    float* P = (float*)d_ws;  // 4096 + 12 floats

    hipLaunchKernelGGL(phynn_pack, dim3(1), dim3(192), 0, stream,
                       Wm1, bm1, Wm2, bm2, Wc1, bc1, Wc2, bc2,
                       Wg1, bg1, Wg2, bg2, Wt1, bt1, Wt2, bt2, P);

    const int half   = B / 2;
    const int blocks = (half + 255) / 256;
    hipLaunchKernelGGL(phynn_main, dim3(blocks), dim3(256), 0, stream,
                       (const float2*)q, (const float2*)qd, (const float2*)u,
                       P, (float*)d_out, B);
}

// Round 3
// 90.184 us; speedup vs baseline: 1.2297x; 1.2297x over previous
//
#include <hip/hip_runtime.h>

#define HID 128
#define EPSM 1e-3f
#define KLOG2E 2.8853900817779268f   // 2*log2(e): folded into layer-1 weights

typedef __fp16 h2 __attribute__((ext_vector_type(2)));

__device__ __forceinline__ h2 as_h2(float f){ union U{float f; h2 h;} u; u.f = f; return u.h; }
__device__ __forceinline__ float h2_bits(h2 h){ union U{h2 h; float f;} u; u.h = h; return u.f; }

__device__ __forceinline__ float fdot2f(h2 a, h2 b, float c){
#if __has_builtin(__builtin_amdgcn_fdot2)
    return __builtin_amdgcn_fdot2(a, b, c, false);
#else
    return fmaf((float)a.x, (float)b.x, fmaf((float)a.y, (float)b.y, c));
#endif
}
__device__ __forceinline__ h2 pkrtz(float a, float b){
#if __has_builtin(__builtin_amdgcn_cvt_pkrtz)
    return __builtin_amdgcn_cvt_pkrtz(a, b);
#else
    h2 r; r.x = (__fp16)a; r.y = (__fp16)b; return r;
#endif
}
__device__ __forceinline__ float aexp2(float x){
#if __has_builtin(__builtin_amdgcn_exp2f)
    return __builtin_amdgcn_exp2f(x);
#else
    return __expf(0.6931471805599453f * x);
#endif
}
__device__ __forceinline__ float arcp(float x){
#if __has_builtin(__builtin_amdgcn_rcpf)
    return __builtin_amdgcn_rcpf(x);
#else
    return 1.0f / x;
#endif
}
// tanh(x) where a = 2*log2(e)*x is the pre-scaled argument
__device__ __forceinline__ float tanh_s(float a){
    float t = aexp2(a);
    float r = arcp(t + 1.0f);
    return fmaf(-2.0f, r, 1.0f);
}

// ---------------------------------------------------------------------------
// Per neuron-PAIR record: 10 float4 (40 floats). Mass MLP stays fp32 (it feeds
// the SPD solve; M-errors amplify ~1e6x). grav/cor/torque use packed f16 with
// f32 accumulation via v_dot2_f32_f16. Layer-1 weights/biases pre-scaled by
// 2*log2(e) so tanh needs no argument multiply.
// ---------------------------------------------------------------------------
__device__ __forceinline__ float h2f(float a, float b){
    h2 h; h.x = (__fp16)a; h.y = (__fp16)b; return h2_bits(h);
}

__global__ void phynn_pack(const float* __restrict__ Wm1, const float* __restrict__ bm1,
                           const float* __restrict__ Wm2, const float* __restrict__ bm2,
                           const float* __restrict__ Wc1, const float* __restrict__ bc1,
                           const float* __restrict__ Wc2, const float* __restrict__ bc2,
                           const float* __restrict__ Wg1, const float* __restrict__ bg1,
                           const float* __restrict__ Wg2, const float* __restrict__ bg2,
                           const float* __restrict__ Wt1, const float* __restrict__ bt1,
                           const float* __restrict__ Wt2, const float* __restrict__ bt2,
                           float* __restrict__ P)
{
    const float k = KLOG2E;
    int p = threadIdx.x;
    if (p < 64) {
        int n0 = 2*p, n1 = 2*p + 1;
        float* o = P + p * 40;
        // v0..v2: mass MLP (fp32), weights pre-scaled by k; L2 cols for L00,L10,L11
        o[0]  = k*Wm1[2*n0];   o[1]  = k*Wm1[2*n0+1]; o[2]  = k*bm1[n0];     o[3]  = Wm2[n0];
        o[4]  = Wm2[256+n0];   o[5]  = Wm2[384+n0];   o[6]  = k*Wm1[2*n1];   o[7]  = k*Wm1[2*n1+1];
        o[8]  = k*bm1[n1];     o[9]  = Wm2[n1];       o[10] = Wm2[256+n1];   o[11] = Wm2[384+n1];
        // v3: grav L1 (f16 pairs + f32 scaled biases)
        o[12] = h2f(k*Wg1[2*n0], k*Wg1[2*n0+1]);
        o[13] = h2f(k*Wg1[2*n1], k*Wg1[2*n1+1]);
        o[14] = k*bg1[n0];     o[15] = k*bg1[n1];
        // v4: grav L2 (neuron-pair packed), cor L1 n0
        o[16] = h2f(Wg2[n0],      Wg2[n1]);
        o[17] = h2f(Wg2[128+n0],  Wg2[128+n1]);
        o[18] = h2f(k*Wc1[4*n0],   k*Wc1[4*n0+1]);
        o[19] = h2f(k*Wc1[4*n0+2], k*Wc1[4*n0+3]);
        // v5: cor L1 n1 + biases
        o[20] = h2f(k*Wc1[4*n1],   k*Wc1[4*n1+1]);
        o[21] = h2f(k*Wc1[4*n1+2], k*Wc1[4*n1+3]);
        o[22] = k*bc1[n0];     o[23] = k*bc1[n1];
        // v6: cor L2 pair-packed
        o[24] = h2f(Wc2[n0],      Wc2[n1]);
        o[25] = h2f(Wc2[128+n0],  Wc2[128+n1]);
        o[26] = h2f(Wc2[256+n0],  Wc2[256+n1]);
        o[27] = h2f(Wc2[384+n0],  Wc2[384+n1]);
        // v7: torque L1 n0
        o[28] = h2f(k*Wt1[6*n0],   k*Wt1[6*n0+1]);
        o[29] = h2f(k*Wt1[6*n0+2], k*Wt1[6*n0+3]);
        o[30] = h2f(k*Wt1[6*n0+4], k*Wt1[6*n0+5]);
        o[31] = k*bt1[n0];
        // v8: torque L1 n1
        o[32] = h2f(k*Wt1[6*n1],   k*Wt1[6*n1+1]);
        o[33] = h2f(k*Wt1[6*n1+2], k*Wt1[6*n1+3]);
        o[34] = h2f(k*Wt1[6*n1+4], k*Wt1[6*n1+5]);
        o[35] = k*bt1[n1];
        // v9: torque L2 pair-packed
        o[36] = h2f(Wt2[n0],     Wt2[n1]);
        o[37] = h2f(Wt2[128+n0], Wt2[128+n1]);
        o[38] = 0.f; o[39] = 0.f;
    }
    if (p == 64) {
        float* t = P + 2560;
        t[0] = bm2[0]; t[1] = bm2[1]; t[2]  = bm2[2]; t[3]  = bm2[3];
        t[4] = bc2[0]; t[5] = bc2[1]; t[6]  = bc2[2]; t[7]  = bc2[3];
        t[8] = bg2[0]; t[9] = bg2[1]; t[10] = bt2[0]; t[11] = bt2[1];
    }
}

#define NPE 2

__global__ __launch_bounds__(256, 4) void phynn_main(
    const float2* __restrict__ q, const float2* __restrict__ qd, const float2* __restrict__ u,
    const float* __restrict__ P, float* __restrict__ out, int B)
{
    __shared__ float4 Ws[640 + 3];
    const float4* Pv = (const float4*)P;
    for (int t = threadIdx.x; t < 643; t += 256) Ws[t] = Pv[t];
    __syncthreads();

    const int half = B >> 1;
    const int tid  = blockIdx.x * 256 + threadIdx.x;
    if (tid >= half) return;

    int e[NPE];
    e[0] = tid;
    e[1] = tid + half;

    float q0[NPE], q1[NPE], d0[NPE], d1[NPE], u0[NPE], u1[NPE];
    h2 qh[NPE], dh[NPE], uh[NPE];
    #pragma unroll
    for (int s = 0; s < NPE; ++s) {
        float2 vq = q[e[s]];  q0[s] = vq.x; q1[s] = vq.y;
        float2 vd = qd[e[s]]; d0[s] = vd.x; d1[s] = vd.y;
        float2 vu = u[e[s]];  u0[s] = vu.x; u1[s] = vu.y;
        qh[s] = pkrtz(q0[s], q1[s]);
        dh[s] = pkrtz(d0[s], d1[s]);
        uh[s] = pkrtz(u0[s], u1[s]);
    }

    float aL0[NPE] = {}, aL2[NPE] = {}, aL3[NPE] = {};
    float aC0[NPE] = {}, aC1[NPE] = {}, aC2[NPE] = {}, aC3[NPE] = {};
    float aG0[NPE] = {}, aG1[NPE] = {};
    float aT0[NPE] = {}, aT1[NPE] = {};

    #pragma unroll 2
    for (int p = 0; p < 64; ++p) {
        const float4 v0 = Ws[p*10+0];
        const float4 v1 = Ws[p*10+1];
        const float4 v2 = Ws[p*10+2];
        const float4 v3 = Ws[p*10+3];
        const float4 v4 = Ws[p*10+4];
        const float4 v5 = Ws[p*10+5];
        const float4 v6 = Ws[p*10+6];
        const float4 v7 = Ws[p*10+7];
        const float4 v8 = Ws[p*10+8];
        const float4 v9 = Ws[p*10+9];

        const h2 gw0 = as_h2(v3.x), gw1 = as_h2(v3.y);
        const h2 gl0 = as_h2(v4.x), gl1 = as_h2(v4.y);
        const h2 c0a = as_h2(v4.z), c0b = as_h2(v4.w);
        const h2 c1a = as_h2(v5.x), c1b = as_h2(v5.y);
        const h2 cl0 = as_h2(v6.x), cl1 = as_h2(v6.y), cl2 = as_h2(v6.z), cl3 = as_h2(v6.w);
        const h2 t0a = as_h2(v7.x), t0b = as_h2(v7.y), t0c = as_h2(v7.z);
        const h2 t1a = as_h2(v8.x), t1b = as_h2(v8.y), t1c = as_h2(v8.z);
        const h2 tl0 = as_h2(v9.x), tl1 = as_h2(v9.y);

        #pragma unroll
        for (int s = 0; s < NPE; ++s) {
            // mass MLP — fp32
            float am0 = fmaf(v0.x, q0[s], fmaf(v0.y, q1[s], v0.z));
            float am1 = fmaf(v1.z, q0[s], fmaf(v1.w, q1[s], v2.x));
            float hm0 = tanh_s(am0);
            float hm1 = tanh_s(am1);
            aL0[s] = fmaf(v0.w, hm0, fmaf(v2.y, hm1, aL0[s]));
            aL2[s] = fmaf(v1.x, hm0, fmaf(v2.z, hm1, aL2[s]));
            aL3[s] = fmaf(v1.y, hm0, fmaf(v2.w, hm1, aL3[s]));
            // gravity MLP — f16 dot2
            float ag0 = fdot2f(gw0, qh[s], v3.z);
            float ag1 = fdot2f(gw1, qh[s], v3.w);
            h2 hg = pkrtz(tanh_s(ag0), tanh_s(ag1));
            aG0[s] = fdot2f(gl0, hg, aG0[s]);
            aG1[s] = fdot2f(gl1, hg, aG1[s]);
            // Coriolis MLP — f16 dot2
            float ac0 = fdot2f(c0a, qh[s], fdot2f(c0b, dh[s], v5.z));
            float ac1 = fdot2f(c1a, qh[s], fdot2f(c1b, dh[s], v5.w));
            h2 hc = pkrtz(tanh_s(ac0), tanh_s(ac1));
            aC0[s] = fdot2f(cl0, hc, aC0[s]);
            aC1[s] = fdot2f(cl1, hc, aC1[s]);
            aC2[s] = fdot2f(cl2, hc, aC2[s]);
            aC3[s] = fdot2f(cl3, hc, aC3[s]);
            // torque MLP — f16 dot2
            float at0 = fdot2f(t0a, qh[s], fdot2f(t0b, dh[s], fdot2f(t0c, uh[s], v7.w)));
            float at1 = fdot2f(t1a, qh[s], fdot2f(t1b, dh[s], fdot2f(t1c, uh[s], v8.w)));
            h2 ht = pkrtz(tanh_s(at0), tanh_s(at1));
            aT0[s] = fdot2f(tl0, ht, aT0[s]);
            aT1[s] = fdot2f(tl1, ht, aT1[s]);
        }
    }

    const float4 bm2v = Ws[640];
    const float4 bc2v = Ws[641];
    const float4 bgt  = Ws[642];

    float*  outf  = out;
    float2* o_qdd = (float2*)outf;
    float4* o_M   = (float4*)(outf + (size_t)2 * B);
    float4* o_C   = (float4*)(outf + (size_t)6 * B);
    float2* o_g   = (float2*)(outf + (size_t)10 * B);
    float2* o_t   = (float2*)(outf + (size_t)12 * B);

    #pragma unroll
    for (int s = 0; s < NPE; ++s) {
        float l00 = aL0[s] + bm2v.x;
        float l10 = aL2[s] + bm2v.z;
        float l11 = aL3[s] + bm2v.w;
        float M00 = fmaf(l00, l00, EPSM);
        float M01 = l00 * l10;
        float M11 = fmaf(l10, l10, fmaf(l11, l11, EPSM));

        float C00 = aC0[s] + bc2v.x;
        float C01 = aC1[s] + bc2v.y;
        float C10 = aC2[s] + bc2v.z;
        float C11 = aC3[s] + bc2v.w;

        float g0 = aG0[s] + bgt.x;
        float g1 = aG1[s] + bgt.y;
        float t0 = aT0[s] + bgt.z;
        float t1 = aT1[s] + bgt.w;

        float rhs0 = u0[s] - fmaf(C00, d0[s], C01 * d1[s]) - g0 - t0;
        float rhs1 = u1[s] - fmaf(C10, d0[s], C11 * d1[s]) - g1 - t1;

        float det = fmaf(M00, M11, -(M01 * M01));
        float r0  = arcp(det);
        float rdet = r0 * fmaf(-det, r0, 2.0f);  // one Newton step: ~1e-12 rel
        float qdd0 = fmaf(M11, rhs0, -(M01 * rhs1)) * rdet;
        float qdd1 = fmaf(M00, rhs1, -(M01 * rhs0)) * rdet;

        o_qdd[e[s]] = make_float2(qdd0, qdd1);
        o_M[e[s]]   = make_float4(M00, M01, M01, M11);
        o_C[e[s]]   = make_float4(C00, C01, C10, C11);
        o_g[e[s]]   = make_float2(g0, g1);
        o_t[e[s]]   = make_float2(t0, t1);
    }
}

extern "C" void kernel_launch(void* const* d_in, const int* in_sizes, int n_in,
                              void* d_out, int out_size, void* d_ws, size_t ws_size,
                              hipStream_t stream)
{
    const float* q   = (const float*)d_in[0];
    const float* qd  = (const float*)d_in[1];
    const float* u   = (const float*)d_in[2];
    const float* Wm1 = (const float*)d_in[3];
    const float* bm1 = (const float*)d_in[4];
    const float* Wm2 = (const float*)d_in[5];
    const float* bm2 = (const float*)d_in[6];
    const float* Wc1 = (const float*)d_in[7];
    const float* bc1 = (const float*)d_in[8];
    const float* Wc2 = (const float*)d_in[9];
    const float* bc2 = (const float*)d_in[10];
    const float* Wg1 = (const float*)d_in[11];
    const float* bg1 = (const float*)d_in[12];
    const float* Wg2 = (const float*)d_in[13];
    const float* bg2 = (const float*)d_in[14];
    const float* Wt1 = (const float*)d_in[15];
    const float* bt1 = (const float*)d_in[16];
    const float* Wt2 = (const float*)d_in[17];
    const float* bt2 = (const float*)d_in[18];

    const int B = in_sizes[0] / 2;
    float* P = (float*)d_ws;  // 2560 + 12 floats

    hipLaunchKernelGGL(phynn_pack, dim3(1), dim3(128), 0, stream,
                       Wm1, bm1, Wm2, bm2, Wc1, bc1, Wc2, bc2,
                       Wg1, bg1, Wg2, bg2, Wt1, bt1, Wt2, bt2, P);

    const int half   = B / 2;
    const int blocks = (half + 255) / 256;
    hipLaunchKernelGGL(phynn_main, dim3(blocks), dim3(256), 0, stream,
                       (const float2*)q, (const float2*)qd, (const float2*)u,
                       P, (float*)d_out, B);
}